// Round 1
// baseline (29120.041 us; speedup 1.0000x reference)
//
#include <hip/hip_runtime.h>
#include <math.h>

#define Bb 32
#define Ss 256
#define Vv 10000
#define Ee 512
#define Hh 1024
#define Ll 3
#define FH 4096

__device__ __forceinline__ float sigf(float x) { return 1.0f / (1.0f + expf(-x)); }

// ---------------------------------------------------------------------------
// K1: layer-norm over seq dim of fix_pred, then per-layer mask/gate scalars.
// grid = 32 blocks (one per batch row b), 256 threads (one per s).
// mask/gate layout: [L][S][B] -> idx l*8192 + s*32 + b
// ---------------------------------------------------------------------------
__global__ __launch_bounds__(256) void maskgate_kernel(
    const float* __restrict__ fp_in, float* __restrict__ mask, float* __restrict__ gate)
{
    __shared__ float red[256];
    int b = blockIdx.x, t = threadIdx.x;
    float v = fp_in[b * Ss + t];
    red[t] = v;
    __syncthreads();
    for (int o = 128; o > 0; o >>= 1) { if (t < o) red[t] += red[t + o]; __syncthreads(); }
    float mu = red[0] * (1.0f / Ss);
    __syncthreads();
    float d = v - mu;
    red[t] = d * d;
    __syncthreads();
    for (int o = 128; o > 0; o >>= 1) { if (t < o) red[t] += red[t + o]; __syncthreads(); }
    float var = red[0] * (1.0f / Ss);
    float fp = d * (1.0f / sqrtf(var + 1e-5f));
    fp = (fp + 1.96f) / 3.92f * 12.0f;
    float alpha0 = (11.0f - fp) * 0.25f;   // RESCALE = 12//3 = 4
    for (int l = 0; l < Ll; ++l) {
        float a = alpha0 - (float)l;
        float m = sigf(a);
        float g = sigf(a + 1.0f) - m;
        mask[l * (Ss * Bb) + t * Bb + b] = m;
        gate[l * (Ss * Bb) + t * Bb + b] = g;
    }
}

// ---------------------------------------------------------------------------
// Generic fp32 NT GEMM: C[M,N] = A[M,K] * B[N,K]^T (+bias, +mode-specific A/C)
// 64x64 tile, BK=16, 256 threads, 4x4 micro-tile per thread.
// MODE 0: A gathered from emb via src; C = input_x ([S,B,H], row r = s*32+b)
// MODE 1: A = input_x * gate        (layer 0: x == 0); C = G chunk (+bi+bh)
// MODE 2: A = x + (input_x - x)*gate;                  C = G chunk (+bi+bh)
// MODE 3: A plain; C = tanh(acc + bias)   (FC1 -> hid)
// MODE 4: A plain; C -> d_out permuted [B,S,V]         (FC2)
// ---------------------------------------------------------------------------
template <int MODE>
__global__ __launch_bounds__(256) void gemm_nt(
    const float* __restrict__ Amat, const float* __restrict__ Bmat,
    const float* __restrict__ bias1, const float* __restrict__ bias2,
    float* __restrict__ Cmat, int M, int N, int K,
    const int* __restrict__ srcIdx, const float* __restrict__ embTab,
    const float* __restrict__ xb, const float* __restrict__ ixb,
    const float* __restrict__ gateArr, int rowOff, float* __restrict__ outDst)
{
    __shared__ float As[16][68];
    __shared__ float Bs[16][68];
    int t = threadIdx.x;
    int tx = t & 15, ty = t >> 4;
    int n0 = blockIdx.x * 64, m0 = blockIdx.y * 64;
    int li = t >> 2;          // 0..63: tile row loaded by this thread
    int lk = (t & 3) * 4;     // 0,4,8,12: k offset (float4)
    float acc[4][4];
#pragma unroll
    for (int y = 0; y < 4; ++y)
#pragma unroll
        for (int x = 0; x < 4; ++x) acc[y][x] = 0.0f;

    for (int k0 = 0; k0 < K; k0 += 16) {
        float a0, a1, a2, a3;
        {
            int r = m0 + li;
            if (MODE == 0) {
                int idx = srcIdx[(r & 31) * Ss + (r >> 5)];
                float4 v = *(const float4*)(embTab + (size_t)idx * K + (k0 + lk));
                a0 = v.x; a1 = v.y; a2 = v.z; a3 = v.w;
            } else if (MODE == 1) {
                int rg = rowOff + r;
                float g = gateArr[rg];
                float4 v = *(const float4*)(ixb + (size_t)rg * K + (k0 + lk));
                a0 = v.x * g; a1 = v.y * g; a2 = v.z * g; a3 = v.w * g;
            } else if (MODE == 2) {
                int rg = rowOff + r;
                float g = gateArr[rg];
                float4 vi = *(const float4*)(ixb + (size_t)rg * K + (k0 + lk));
                float4 vx = *(const float4*)(xb + (size_t)rg * K + (k0 + lk));
                a0 = vx.x + (vi.x - vx.x) * g;
                a1 = vx.y + (vi.y - vx.y) * g;
                a2 = vx.z + (vi.z - vx.z) * g;
                a3 = vx.w + (vi.w - vx.w) * g;
            } else {
                float4 v = *(const float4*)(Amat + (size_t)r * K + (k0 + lk));
                a0 = v.x; a1 = v.y; a2 = v.z; a3 = v.w;
            }
        }
        As[lk + 0][li] = a0; As[lk + 1][li] = a1; As[lk + 2][li] = a2; As[lk + 3][li] = a3;
        {
            int n = n0 + li;
            float b0 = 0.f, b1 = 0.f, b2 = 0.f, b3 = 0.f;
            if (n < N) {
                float4 v = *(const float4*)(Bmat + (size_t)n * K + (k0 + lk));
                b0 = v.x; b1 = v.y; b2 = v.z; b3 = v.w;
            }
            Bs[lk + 0][li] = b0; Bs[lk + 1][li] = b1; Bs[lk + 2][li] = b2; Bs[lk + 3][li] = b3;
        }
        __syncthreads();
#pragma unroll
        for (int kk = 0; kk < 16; ++kk) {
            float4 av = *(const float4*)&As[kk][ty * 4];
            float4 bv = *(const float4*)&Bs[kk][tx * 4];
            float avc[4] = {av.x, av.y, av.z, av.w};
            float bvc[4] = {bv.x, bv.y, bv.z, bv.w};
#pragma unroll
            for (int y = 0; y < 4; ++y)
#pragma unroll
                for (int x = 0; x < 4; ++x)
                    acc[y][x] = fmaf(avc[y], bvc[x], acc[y][x]);
        }
        __syncthreads();
    }
#pragma unroll
    for (int y = 0; y < 4; ++y) {
        int r = m0 + ty * 4 + y;
#pragma unroll
        for (int x = 0; x < 4; ++x) {
            int n = n0 + tx * 4 + x;
            if (n < N) {
                float vv = acc[y][x];
                if (MODE == 0) {
                    Cmat[(size_t)r * N + n] = vv + bias1[n];
                } else if (MODE == 1 || MODE == 2) {
                    Cmat[(size_t)r * N + n] = vv + bias1[n] + bias2[n];
                } else if (MODE == 3) {
                    Cmat[(size_t)r * N + n] = tanhf(vv + bias1[n]);
                } else {
                    // r = s*32 + b  ->  out[b][s][n]
                    outDst[((size_t)(r & 31) * Ss + (r >> 5)) * Vv + n] = vv + bias1[n];
                }
            }
        }
    }
}

// ---------------------------------------------------------------------------
// One LSTM time step. grid = 256 blocks; block k owns h indices j0=4k..4k+3
// (16 gate rows). Each thread: b = t&31, rr = t>>5 (q = rr>>1, dd = rr&1),
// computes 2 gate-row dot products over K=1024 (h staged in LDS per 128-chunk).
// G chunk rows already include bi+bh. Double-buffered h (hprev/hnext).
// ---------------------------------------------------------------------------
__global__ __launch_bounds__(256) void lstm_step(
    const float* __restrict__ Gp,     // + s_local*32*4096 (rows [b][4096])
    const float* __restrict__ Wh,     // [4096][1024] for this layer
    const float* __restrict__ maskp,  // + l*8192 + s*32  (index by b)
    const float* __restrict__ hprev,  // [32][1024]
    float* __restrict__ hnext,        // [32][1024]
    float* __restrict__ cbuf,         // [32][1024]
    float* __restrict__ xout)         // x + s*32*1024 (layout [b][1024])
{
    __shared__ float hs[32 * 132];    // h chunk [32][128] padded
    __shared__ float gbuf[16 * 32];   // [q*4+d][b]
    int t = threadIdx.x;
    int b = t & 31, rr = t >> 5;      // rr 0..7
    int q = rr >> 1, dd = rr & 1;
    int j0 = blockIdx.x * 4;
    int row0 = q * Hh + j0 + dd;
    int row1 = row0 + 2;
    const float* w0 = Wh + (size_t)row0 * Hh;
    const float* w1 = Wh + (size_t)row1 * Hh;
    float acc0 = 0.0f, acc1 = 0.0f;

    for (int kc = 0; kc < Hh; kc += 128) {
#pragma unroll
        for (int i = 0; i < 4; ++i) {
            int f4 = i * 256 + t;             // float4 index within 32x128 tile
            int bl = f4 >> 5, k4 = f4 & 31;
            float4 v = *(const float4*)(hprev + bl * Hh + kc + k4 * 4);
            *(float4*)(hs + bl * 132 + k4 * 4) = v;
        }
        __syncthreads();
        const float* hb = hs + b * 132;
#pragma unroll
        for (int k4 = 0; k4 < 32; ++k4) {
            float4 hv = *(const float4*)(hb + k4 * 4);
            float4 wa = *(const float4*)(w0 + kc + k4 * 4);
            float4 wc = *(const float4*)(w1 + kc + k4 * 4);
            acc0 = fmaf(wa.x, hv.x, acc0); acc0 = fmaf(wa.y, hv.y, acc0);
            acc0 = fmaf(wa.z, hv.z, acc0); acc0 = fmaf(wa.w, hv.w, acc0);
            acc1 = fmaf(wc.x, hv.x, acc1); acc1 = fmaf(wc.y, hv.y, acc1);
            acc1 = fmaf(wc.z, hv.z, acc1); acc1 = fmaf(wc.w, hv.w, acc1);
        }
        __syncthreads();
    }
    acc0 += Gp[(size_t)b * FH + row0];
    acc1 += Gp[(size_t)b * FH + row1];
    gbuf[(q * 4 + dd) * 32 + b] = acc0;
    gbuf[(q * 4 + dd + 2) * 32 + b] = acc1;
    __syncthreads();
    if (t < 128) {
        int b2 = t & 31, d2 = t >> 5;   // d2 0..3
        int j = j0 + d2;
        float gi = gbuf[(0 * 4 + d2) * 32 + b2];
        float gf = gbuf[(1 * 4 + d2) * 32 + b2];
        float gg = gbuf[(2 * 4 + d2) * 32 + b2];
        float go = gbuf[(3 * 4 + d2) * 32 + b2];
        float m  = maskp[b2];
        float c_old = cbuf[b2 * Hh + j];
        float h_old = hprev[b2 * Hh + j];
        float ct = sigf(gf) * c_old + sigf(gi) * tanhf(gg);
        float ht = sigf(go) * tanhf(ct);
        float cn = ct + (c_old - ct) * m;
        float hn = ht + (h_old - ht) * m;
        cbuf[b2 * Hh + j] = cn;
        hnext[b2 * Hh + j] = hn;
        xout[b2 * Hh + j] = hn;
    }
}

__global__ __launch_bounds__(256) void init_hc(
    const float* __restrict__ h0, const float* __restrict__ c0,
    float* __restrict__ hb0, float* __restrict__ cb)
{
    int i = blockIdx.x * 256 + threadIdx.x;   // 32768 elements
    hb0[i] = h0[i];
    cb[i] = c0[i];
}

// ---------------------------------------------------------------------------
extern "C" void kernel_launch(void* const* d_in, const int* in_sizes, int n_in,
                              void* d_out, int out_size, void* d_ws, size_t ws_size,
                              hipStream_t stream)
{
    const int*   src      = (const int*)  d_in[0];
    const float* fix_pred = (const float*)d_in[1];
    const float* emb      = (const float*)d_in[2];
    const float* W_lin    = (const float*)d_in[3];
    const float* b_lin    = (const float*)d_in[4];
    const float* W_ih     = (const float*)d_in[5];
    const float* W_hh     = (const float*)d_in[6];
    const float* b_ih     = (const float*)d_in[7];
    const float* b_hh     = (const float*)d_in[8];
    const float* fc_W1    = (const float*)d_in[9];
    const float* fc_b1    = (const float*)d_in[10];
    const float* fc_b2    = (const float*)d_in[12];
    const float* fc_W2    = (const float*)d_in[11];
    const float* h0       = (const float*)d_in[13];
    const float* c0       = (const float*)d_in[14];
    float* out = (float*)d_out;

    // workspace layout (floats)
    float* ws   = (float*)d_ws;
    float* ix   = ws;                   // 8192*1024  = 8388608   input_x [S,B,H]
    float* xbuf = ix + 8388608;         // 8388608               x       [S,B,H]
    float* Gch  = xbuf + 8388608;       // 8388608               G chunk (64 steps) [2048][4096]
    float* hid  = Gch;                  // alias: hid [8192][512] reuses G after layers
    float* hb   = Gch + 8388608;        // 2*32768 double-buffered h
    float* cb   = hb + 65536;           // 32768
    float* mask = cb + 32768;           // 3*8192
    float* gate = mask + 24576;         // 3*8192
    // total = 25,313,280 floats = 101.25 MB

    maskgate_kernel<<<32, 256, 0, stream>>>(fix_pred, mask, gate);

    // input_x = emb[src] @ W_lin^T + b_lin : M=8192 N=1024 K=512
    gemm_nt<0><<<dim3(16, 128), 256, 0, stream>>>(
        nullptr, W_lin, b_lin, nullptr, ix, 8192, 1024, 512,
        src, emb, nullptr, nullptr, nullptr, 0, nullptr);

    for (int l = 0; l < Ll; ++l) {
        init_hc<<<128, 256, 0, stream>>>(h0 + (size_t)l * 32768, c0 + (size_t)l * 32768, hb, cb);
        const float* Wi = W_ih + (size_t)l * FH * Hh;
        const float* Wh = W_hh + (size_t)l * FH * Hh;
        const float* bi = b_ih + (size_t)l * FH;
        const float* bh = b_hh + (size_t)l * FH;
        for (int ch = 0; ch < 4; ++ch) {
            int rowOff = ch * 2048;
            // G = inp_seq @ Wi^T + bi + bh : M=2048 N=4096 K=1024
            if (l == 0) {
                gemm_nt<1><<<dim3(64, 32), 256, 0, stream>>>(
                    nullptr, Wi, bi, bh, Gch, 2048, 4096, 1024,
                    nullptr, nullptr, nullptr, ix, gate + l * 8192, rowOff, nullptr);
            } else {
                gemm_nt<2><<<dim3(64, 32), 256, 0, stream>>>(
                    nullptr, Wi, bi, bh, Gch, 2048, 4096, 1024,
                    nullptr, nullptr, xbuf, ix, gate + l * 8192, rowOff, nullptr);
            }
            for (int sl = 0; sl < 64; ++sl) {
                int s = ch * 64 + sl;
                lstm_step<<<256, 256, 0, stream>>>(
                    Gch + (size_t)sl * 32 * FH,
                    Wh,
                    mask + l * 8192 + s * 32,
                    hb + (s & 1) * 32768,
                    hb + ((s + 1) & 1) * 32768,
                    cb,
                    xbuf + (size_t)s * 32768);
            }
        }
    }

    // hid = tanh(x @ fc_W1^T + fc_b1) : M=8192 N=512 K=1024
    gemm_nt<3><<<dim3(8, 128), 256, 0, stream>>>(
        xbuf, fc_W1, fc_b1, nullptr, hid, 8192, 512, 1024,
        nullptr, nullptr, nullptr, nullptr, nullptr, 0, nullptr);

    // out = hid @ fc_W2^T + fc_b2 : M=8192 N=10000 K=512, permuted store
    gemm_nt<4><<<dim3(157, 128), 256, 0, stream>>>(
        hid, fc_W2, fc_b2, nullptr, nullptr, 8192, 10000, 512,
        nullptr, nullptr, nullptr, nullptr, nullptr, 0, out);
}

// Round 2
// 26237.491 us; speedup vs baseline: 1.1099x; 1.1099x over previous
//
#include <hip/hip_runtime.h>
#include <math.h>

#define Bb 32
#define Ss 256
#define Vv 10000
#define Ee 512
#define Hh 1024
#define Ll 3
#define FH 4096

typedef short short8 __attribute__((ext_vector_type(8)));
typedef float floatx4 __attribute__((ext_vector_type(4)));

__device__ __forceinline__ float sigf(float x) { return 1.0f / (1.0f + expf(-x)); }

// split fp32 -> bf16 hi/lo (RNE). packed u32: low16 = hi, high16 = lo
__device__ __forceinline__ unsigned pack_hl(float x) {
    unsigned u = __float_as_uint(x);
    unsigned r = u + 0x7fff + ((u >> 16) & 1);
    unsigned hi = r >> 16;
    float hf = __uint_as_float(hi << 16);
    float l = x - hf;
    unsigned ul = __float_as_uint(l);
    unsigned rl = ul + 0x7fff + ((ul >> 16) & 1);
    return hi | ((rl >> 16) << 16);
}
__device__ __forceinline__ void split_hl(float x, unsigned short& h, unsigned short& l) {
    unsigned p = pack_hl(x);
    h = (unsigned short)(p & 0xffff);
    l = (unsigned short)(p >> 16);
}

// ---------------------------------------------------------------------------
// pack fp32 weights -> packed bf16 hi/lo u32 (vectorized float4)
// ---------------------------------------------------------------------------
__global__ __launch_bounds__(256) void pack_split(
    const float* __restrict__ src, unsigned* __restrict__ dst, int n4)
{
    int i = blockIdx.x * 256 + threadIdx.x;
    if (i < n4) {
        float4 v = ((const float4*)src)[i];
        uint4 o;
        o.x = pack_hl(v.x); o.y = pack_hl(v.y); o.z = pack_hl(v.z); o.w = pack_hl(v.w);
        ((uint4*)dst)[i] = o;
    }
}

// ---------------------------------------------------------------------------
// K1: layer-norm over seq dim of fix_pred, then per-layer mask/gate scalars.
// mask/gate layout: [L][S][B] -> idx l*8192 + s*32 + b
// ---------------------------------------------------------------------------
__global__ __launch_bounds__(256) void maskgate_kernel(
    const float* __restrict__ fp_in, float* __restrict__ mask, float* __restrict__ gate)
{
    __shared__ float red[256];
    int b = blockIdx.x, t = threadIdx.x;
    float v = fp_in[b * Ss + t];
    red[t] = v;
    __syncthreads();
    for (int o = 128; o > 0; o >>= 1) { if (t < o) red[t] += red[t + o]; __syncthreads(); }
    float mu = red[0] * (1.0f / Ss);
    __syncthreads();
    float d = v - mu;
    red[t] = d * d;
    __syncthreads();
    for (int o = 128; o > 0; o >>= 1) { if (t < o) red[t] += red[t + o]; __syncthreads(); }
    float var = red[0] * (1.0f / Ss);
    float fp = d * (1.0f / sqrtf(var + 1e-5f));
    fp = (fp + 1.96f) / 3.92f * 12.0f;
    float alpha0 = (11.0f - fp) * 0.25f;   // RESCALE = 12//3 = 4
    for (int l = 0; l < Ll; ++l) {
        float a = alpha0 - (float)l;
        float m = sigf(a);
        float g = sigf(a + 1.0f) - m;
        mask[l * (Ss * Bb) + t * Bb + b] = m;
        gate[l * (Ss * Bb) + t * Bb + b] = g;
    }
}

// ---------------------------------------------------------------------------
// fp32 NT GEMM (kept for the two small GEMMs):
// MODE 0: A gathered from emb via src; C = input_x + b_lin
// MODE 3: A plain; C = tanh(acc + bias)   (FC1 -> hid)
// ---------------------------------------------------------------------------
template <int MODE>
__global__ __launch_bounds__(256) void gemm_nt(
    const float* __restrict__ Amat, const float* __restrict__ Bmat,
    const float* __restrict__ bias1,
    float* __restrict__ Cmat, int M, int N, int K,
    const int* __restrict__ srcIdx, const float* __restrict__ embTab)
{
    __shared__ float As[16][68];
    __shared__ float Bs[16][68];
    int t = threadIdx.x;
    int tx = t & 15, ty = t >> 4;
    int n0 = blockIdx.x * 64, m0 = blockIdx.y * 64;
    int li = t >> 2;
    int lk = (t & 3) * 4;
    float acc[4][4];
#pragma unroll
    for (int y = 0; y < 4; ++y)
#pragma unroll
        for (int x = 0; x < 4; ++x) acc[y][x] = 0.0f;

    for (int k0 = 0; k0 < K; k0 += 16) {
        float a0, a1, a2, a3;
        {
            int r = m0 + li;
            if (MODE == 0) {
                int idx = srcIdx[(r & 31) * Ss + (r >> 5)];
                float4 v = *(const float4*)(embTab + (size_t)idx * K + (k0 + lk));
                a0 = v.x; a1 = v.y; a2 = v.z; a3 = v.w;
            } else {
                float4 v = *(const float4*)(Amat + (size_t)r * K + (k0 + lk));
                a0 = v.x; a1 = v.y; a2 = v.z; a3 = v.w;
            }
        }
        As[lk + 0][li] = a0; As[lk + 1][li] = a1; As[lk + 2][li] = a2; As[lk + 3][li] = a3;
        {
            int n = n0 + li;
            float b0 = 0.f, b1 = 0.f, b2 = 0.f, b3 = 0.f;
            if (n < N) {
                float4 v = *(const float4*)(Bmat + (size_t)n * K + (k0 + lk));
                b0 = v.x; b1 = v.y; b2 = v.z; b3 = v.w;
            }
            Bs[lk + 0][li] = b0; Bs[lk + 1][li] = b1; Bs[lk + 2][li] = b2; Bs[lk + 3][li] = b3;
        }
        __syncthreads();
#pragma unroll
        for (int kk = 0; kk < 16; ++kk) {
            float4 av = *(const float4*)&As[kk][ty * 4];
            float4 bv = *(const float4*)&Bs[kk][tx * 4];
            float avc[4] = {av.x, av.y, av.z, av.w};
            float bvc[4] = {bv.x, bv.y, bv.z, bv.w};
#pragma unroll
            for (int y = 0; y < 4; ++y)
#pragma unroll
                for (int x = 0; x < 4; ++x)
                    acc[y][x] = fmaf(avc[y], bvc[x], acc[y][x]);
        }
        __syncthreads();
    }
#pragma unroll
    for (int y = 0; y < 4; ++y) {
        int r = m0 + ty * 4 + y;
#pragma unroll
        for (int x = 0; x < 4; ++x) {
            int n = n0 + tx * 4 + x;
            if (n < N) {
                float vv = acc[y][x];
                if (MODE == 0) Cmat[(size_t)r * N + n] = vv + bias1[n];
                else           Cmat[(size_t)r * N + n] = tanhf(vv + bias1[n]);
            }
        }
    }
}

// ---------------------------------------------------------------------------
// MFMA split-bf16 NT GEMM: C[M,N] = A[M,K] * B[N,K]^T in ~fp32 precision.
// A fp32 (converted hi/lo during staging), B pre-packed u32 (lo16=hi,hi16=lo).
// 128x128 tile, BK=32, 256 threads = 4 waves, each wave 64x64 (4x4 subtiles
// of 16x16x32). 3 MFMAs per subtile per k-slice: ah*bh + al*bh + ah*bl.
// MODE 1: A = ix * gate          (layer 0)    C = G (+bi+bh)
// MODE 2: A = x + (ix - x)*gate  (layers 1+)  C = G (+bi+bh)
// MODE 4: A plain (hid);  store -> out permuted [B,S,V], n guarded
// ---------------------------------------------------------------------------
template <int MODE>
__global__ __launch_bounds__(256) void gemm_mfma(
    const float* __restrict__ Amat, const unsigned* __restrict__ Bp,
    const float* __restrict__ bias1, const float* __restrict__ bias2,
    float* __restrict__ Cmat, int M, int N, int K,
    const float* __restrict__ xb, const float* __restrict__ ixb,
    const float* __restrict__ gateArr, int rowOff,
    float* __restrict__ outDst)
{
    __shared__ unsigned short As_h[128][40];
    __shared__ unsigned short As_l[128][40];
    __shared__ unsigned short Bs_h[128][40];
    __shared__ unsigned short Bs_l[128][40];

    const int t = threadIdx.x;
    const int n0 = blockIdx.x * 128, m0 = blockIdx.y * 128;
    const int lane = t & 63, w = t >> 6;
    const int mb = (w & 1) * 64, nb = (w >> 1) * 64;
    const int row = lane & 15, grp8 = (lane >> 4) * 8;

    // staging assignment: thread t owns tile row t>>1, k-segment (t&1)*16
    const int arow = t >> 1;
    const int kseg = (t & 1) * 16;

    float gblend = 0.0f;
    const float* aptr = nullptr;      // fp32 A row (ix or Amat)
    const float* xptr = nullptr;      // fp32 x row (MODE 2)
    if (MODE == 1 || MODE == 2) {
        int rg = rowOff + m0 + arow;
        gblend = gateArr[rg];
        aptr = ixb + (size_t)rg * K;
        if (MODE == 2) xptr = xb + (size_t)rg * K;
    } else {
        aptr = Amat + (size_t)(m0 + arow) * K;
    }
    const int bn = n0 + arow;
    const unsigned* bptr = Bp + (size_t)(bn < N ? bn : 0) * K;
    const bool bvalid = (bn < N);

    floatx4 acc[4][4];
#pragma unroll
    for (int i = 0; i < 4; ++i)
#pragma unroll
        for (int j = 0; j < 4; ++j)
            acc[i][j] = (floatx4){0.f, 0.f, 0.f, 0.f};

    for (int k0 = 0; k0 < K; k0 += 32) {
        // ---- stage A (fp32 -> hi/lo bf16) ----
        unsigned short hbuf[16], lbuf[16];
#pragma unroll
        for (int u = 0; u < 4; ++u) {
            float4 vi = *(const float4*)(aptr + k0 + kseg + u * 4);
            float vals[4] = {vi.x, vi.y, vi.z, vi.w};
            if (MODE == 1) {
#pragma unroll
                for (int c = 0; c < 4; ++c) vals[c] *= gblend;
            } else if (MODE == 2) {
                float4 vx = *(const float4*)(xptr + k0 + kseg + u * 4);
                float xs[4] = {vx.x, vx.y, vx.z, vx.w};
#pragma unroll
                for (int c = 0; c < 4; ++c) vals[c] = xs[c] + (vals[c] - xs[c]) * gblend;
            }
#pragma unroll
            for (int c = 0; c < 4; ++c) split_hl(vals[c], hbuf[u * 4 + c], lbuf[u * 4 + c]);
        }
        {
            uint4 ph, pl;
            ph.x = hbuf[0] | ((unsigned)hbuf[1] << 16);
            ph.y = hbuf[2] | ((unsigned)hbuf[3] << 16);
            ph.z = hbuf[4] | ((unsigned)hbuf[5] << 16);
            ph.w = hbuf[6] | ((unsigned)hbuf[7] << 16);
            pl.x = lbuf[0] | ((unsigned)lbuf[1] << 16);
            pl.y = lbuf[2] | ((unsigned)lbuf[3] << 16);
            pl.z = lbuf[4] | ((unsigned)lbuf[5] << 16);
            pl.w = lbuf[6] | ((unsigned)lbuf[7] << 16);
            *(uint4*)&As_h[arow][kseg] = ph;
            *(uint4*)&As_l[arow][kseg] = pl;
            uint4 ph2, pl2;
            ph2.x = hbuf[8] | ((unsigned)hbuf[9] << 16);
            ph2.y = hbuf[10] | ((unsigned)hbuf[11] << 16);
            ph2.z = hbuf[12] | ((unsigned)hbuf[13] << 16);
            ph2.w = hbuf[14] | ((unsigned)hbuf[15] << 16);
            pl2.x = lbuf[8] | ((unsigned)lbuf[9] << 16);
            pl2.y = lbuf[10] | ((unsigned)lbuf[11] << 16);
            pl2.z = lbuf[12] | ((unsigned)lbuf[13] << 16);
            pl2.w = lbuf[14] | ((unsigned)lbuf[15] << 16);
            *(uint4*)&As_h[arow][kseg + 8] = ph2;
            *(uint4*)&As_l[arow][kseg + 8] = pl2;
        }
        // ---- stage B (pre-packed) ----
        {
            unsigned short bh[16], bl[16];
            if (bvalid) {
#pragma unroll
                for (int u = 0; u < 4; ++u) {
                    uint4 q = *(const uint4*)(bptr + k0 + kseg + u * 4);
                    unsigned qs[4] = {q.x, q.y, q.z, q.w};
#pragma unroll
                    for (int c = 0; c < 4; ++c) {
                        bh[u * 4 + c] = (unsigned short)(qs[c] & 0xffff);
                        bl[u * 4 + c] = (unsigned short)(qs[c] >> 16);
                    }
                }
            } else {
#pragma unroll
                for (int c = 0; c < 16; ++c) { bh[c] = 0; bl[c] = 0; }
            }
            uint4 ph, pl;
            ph.x = bh[0] | ((unsigned)bh[1] << 16);
            ph.y = bh[2] | ((unsigned)bh[3] << 16);
            ph.z = bh[4] | ((unsigned)bh[5] << 16);
            ph.w = bh[6] | ((unsigned)bh[7] << 16);
            pl.x = bl[0] | ((unsigned)bl[1] << 16);
            pl.y = bl[2] | ((unsigned)bl[3] << 16);
            pl.z = bl[4] | ((unsigned)bl[5] << 16);
            pl.w = bl[6] | ((unsigned)bl[7] << 16);
            *(uint4*)&Bs_h[arow][kseg] = ph;
            *(uint4*)&Bs_l[arow][kseg] = pl;
            uint4 ph2, pl2;
            ph2.x = bh[8] | ((unsigned)bh[9] << 16);
            ph2.y = bh[10] | ((unsigned)bh[11] << 16);
            ph2.z = bh[12] | ((unsigned)bh[13] << 16);
            ph2.w = bh[14] | ((unsigned)bh[15] << 16);
            pl2.x = bl[8] | ((unsigned)bl[9] << 16);
            pl2.y = bl[10] | ((unsigned)bl[11] << 16);
            pl2.z = bl[12] | ((unsigned)bl[13] << 16);
            pl2.w = bl[14] | ((unsigned)bl[15] << 16);
            *(uint4*)&Bs_h[arow][kseg + 8] = ph2;
            *(uint4*)&Bs_l[arow][kseg + 8] = pl2;
        }
        __syncthreads();
        // ---- MFMA: 4x4 subtiles x 3 products ----
        short8 ah[4], al[4], bh8[4], bl8[4];
#pragma unroll
        for (int i = 0; i < 4; ++i) {
            ah[i] = *(const short8*)&As_h[mb + i * 16 + row][grp8];
            al[i] = *(const short8*)&As_l[mb + i * 16 + row][grp8];
            bh8[i] = *(const short8*)&Bs_h[nb + i * 16 + row][grp8];
            bl8[i] = *(const short8*)&Bs_l[nb + i * 16 + row][grp8];
        }
#pragma unroll
        for (int i = 0; i < 4; ++i)
#pragma unroll
            for (int j = 0; j < 4; ++j) {
                acc[i][j] = __builtin_amdgcn_mfma_f32_16x16x32_bf16(ah[i], bh8[j], acc[i][j], 0, 0, 0);
                acc[i][j] = __builtin_amdgcn_mfma_f32_16x16x32_bf16(al[i], bh8[j], acc[i][j], 0, 0, 0);
                acc[i][j] = __builtin_amdgcn_mfma_f32_16x16x32_bf16(ah[i], bl8[j], acc[i][j], 0, 0, 0);
            }
        __syncthreads();
    }

    // ---- epilogue ----
    const int grp = lane >> 4;
#pragma unroll
    for (int i = 0; i < 4; ++i) {
        int mbase = m0 + mb + i * 16 + grp * 4;
#pragma unroll
        for (int j = 0; j < 4; ++j) {
            int n = n0 + nb + j * 16 + (lane & 15);
#pragma unroll
            for (int r = 0; r < 4; ++r) {
                float vv = acc[i][j][r];
                int mm = mbase + r;
                if (MODE == 4) {
                    if (n < N)
                        outDst[((size_t)(mm & 31) * Ss + (mm >> 5)) * Vv + n] = vv + bias1[n];
                } else {
                    Cmat[(size_t)mm * N + n] = vv + bias1[n] + bias2[n];
                }
            }
        }
    }
}

// ---------------------------------------------------------------------------
// One LSTM time step (unchanged from Round 0 — correct).
// ---------------------------------------------------------------------------
__global__ __launch_bounds__(256) void lstm_step(
    const float* __restrict__ Gp,
    const float* __restrict__ Wh,
    const float* __restrict__ maskp,
    const float* __restrict__ hprev,
    float* __restrict__ hnext,
    float* __restrict__ cbuf,
    float* __restrict__ xout)
{
    __shared__ float hs[32 * 132];
    __shared__ float gbuf[16 * 32];
    int t = threadIdx.x;
    int b = t & 31, rr = t >> 5;
    int q = rr >> 1, dd = rr & 1;
    int j0 = blockIdx.x * 4;
    int row0 = q * Hh + j0 + dd;
    int row1 = row0 + 2;
    const float* w0 = Wh + (size_t)row0 * Hh;
    const float* w1 = Wh + (size_t)row1 * Hh;
    float acc0 = 0.0f, acc1 = 0.0f;

    for (int kc = 0; kc < Hh; kc += 128) {
#pragma unroll
        for (int i = 0; i < 4; ++i) {
            int f4 = i * 256 + t;
            int bl = f4 >> 5, k4 = f4 & 31;
            float4 v = *(const float4*)(hprev + bl * Hh + kc + k4 * 4);
            *(float4*)(hs + bl * 132 + k4 * 4) = v;
        }
        __syncthreads();
        const float* hb = hs + b * 132;
#pragma unroll
        for (int k4 = 0; k4 < 32; ++k4) {
            float4 hv = *(const float4*)(hb + k4 * 4);
            float4 wa = *(const float4*)(w0 + kc + k4 * 4);
            float4 wc = *(const float4*)(w1 + kc + k4 * 4);
            acc0 = fmaf(wa.x, hv.x, acc0); acc0 = fmaf(wa.y, hv.y, acc0);
            acc0 = fmaf(wa.z, hv.z, acc0); acc0 = fmaf(wa.w, hv.w, acc0);
            acc1 = fmaf(wc.x, hv.x, acc1); acc1 = fmaf(wc.y, hv.y, acc1);
            acc1 = fmaf(wc.z, hv.z, acc1); acc1 = fmaf(wc.w, hv.w, acc1);
        }
        __syncthreads();
    }
    acc0 += Gp[(size_t)b * FH + row0];
    acc1 += Gp[(size_t)b * FH + row1];
    gbuf[(q * 4 + dd) * 32 + b] = acc0;
    gbuf[(q * 4 + dd + 2) * 32 + b] = acc1;
    __syncthreads();
    if (t < 128) {
        int b2 = t & 31, d2 = t >> 5;
        int j = j0 + d2;
        float gi = gbuf[(0 * 4 + d2) * 32 + b2];
        float gf = gbuf[(1 * 4 + d2) * 32 + b2];
        float gg = gbuf[(2 * 4 + d2) * 32 + b2];
        float go = gbuf[(3 * 4 + d2) * 32 + b2];
        float m  = maskp[b2];
        float c_old = cbuf[b2 * Hh + j];
        float h_old = hprev[b2 * Hh + j];
        float ct = sigf(gf) * c_old + sigf(gi) * tanhf(gg);
        float ht = sigf(go) * tanhf(ct);
        float cn = ct + (c_old - ct) * m;
        float hn = ht + (h_old - ht) * m;
        cbuf[b2 * Hh + j] = cn;
        hnext[b2 * Hh + j] = hn;
        xout[b2 * Hh + j] = hn;
    }
}

__global__ __launch_bounds__(256) void init_hc(
    const float* __restrict__ h0, const float* __restrict__ c0,
    float* __restrict__ hb0, float* __restrict__ cb)
{
    int i = blockIdx.x * 256 + threadIdx.x;
    hb0[i] = h0[i];
    cb[i] = c0[i];
}

// ---------------------------------------------------------------------------
extern "C" void kernel_launch(void* const* d_in, const int* in_sizes, int n_in,
                              void* d_out, int out_size, void* d_ws, size_t ws_size,
                              hipStream_t stream)
{
    const int*   src      = (const int*)  d_in[0];
    const float* fix_pred = (const float*)d_in[1];
    const float* emb      = (const float*)d_in[2];
    const float* W_lin    = (const float*)d_in[3];
    const float* b_lin    = (const float*)d_in[4];
    const float* W_ih     = (const float*)d_in[5];
    const float* W_hh     = (const float*)d_in[6];
    const float* b_ih     = (const float*)d_in[7];
    const float* b_hh     = (const float*)d_in[8];
    const float* fc_W1    = (const float*)d_in[9];
    const float* fc_b1    = (const float*)d_in[10];
    const float* fc_W2    = (const float*)d_in[11];
    const float* fc_b2    = (const float*)d_in[12];
    const float* h0       = (const float*)d_in[13];
    const float* c0       = (const float*)d_in[14];
    float* out = (float*)d_out;

    // workspace layout (floats)
    float* ws    = (float*)d_ws;
    float* ix    = ws;                    // 8388608  input_x [S*B][H]
    float* xbuf  = ix + 8388608;          // 8388608  x       [S*B][H]
    float* Gch   = xbuf + 8388608;        // 8388608  G chunk [2048][4096]
    float* hid   = Gch;                   // alias: hid [8192][512]
    unsigned* wpack = (unsigned*)(Gch + 8388608);  // 4194304 u32: Wi[l] packed
    float* hb    = (float*)(wpack + 4194304);      // 65536 (double-buffered h)
    float* cb    = hb + 65536;            // 32768
    float* mask  = cb + 32768;            // 24576
    float* gate  = mask + 24576;          // 24576
    // total = 29,507,584 floats = 118.0 MB

    maskgate_kernel<<<32, 256, 0, stream>>>(fix_pred, mask, gate);

    // input_x = emb[src] @ W_lin^T + b_lin : M=8192 N=1024 K=512 (fp32)
    gemm_nt<0><<<dim3(16, 128), 256, 0, stream>>>(
        nullptr, W_lin, b_lin, ix, 8192, 1024, 512, src, emb);

    for (int l = 0; l < Ll; ++l) {
        pack_split<<<4096, 256, 0, stream>>>(W_ih + (size_t)l * FH * Hh, wpack, 1048576);
        init_hc<<<128, 256, 0, stream>>>(h0 + (size_t)l * 32768, c0 + (size_t)l * 32768, hb, cb);
        const float* Wh = W_hh + (size_t)l * FH * Hh;
        const float* bi = b_ih + (size_t)l * FH;
        const float* bh = b_hh + (size_t)l * FH;
        for (int ch = 0; ch < 4; ++ch) {
            int rowOff = ch * 2048;
            // G = inp_seq @ Wi^T + bi + bh : M=2048 N=4096 K=1024 (MFMA split-3)
            if (l == 0) {
                gemm_mfma<1><<<dim3(32, 16), 256, 0, stream>>>(
                    nullptr, wpack, bi, bh, Gch, 2048, 4096, 1024,
                    nullptr, ix, gate + l * 8192, rowOff, nullptr);
            } else {
                gemm_mfma<2><<<dim3(32, 16), 256, 0, stream>>>(
                    nullptr, wpack, bi, bh, Gch, 2048, 4096, 1024,
                    xbuf, ix, gate + l * 8192, rowOff, nullptr);
            }
            for (int sl = 0; sl < 64; ++sl) {
                int s = ch * 64 + sl;
                lstm_step<<<256, 256, 0, stream>>>(
                    Gch + (size_t)sl * 32 * FH,
                    Wh,
                    mask + l * 8192 + s * 32,
                    hb + (s & 1) * 32768,
                    hb + ((s + 1) & 1) * 32768,
                    cb,
                    xbuf + (size_t)s * 32768);
            }
        }
    }

    // hid = tanh(x @ fc_W1^T + fc_b1) : M=8192 N=512 K=1024 (fp32)
    gemm_nt<3><<<dim3(8, 128), 256, 0, stream>>>(
        xbuf, fc_W1, fc_b1, hid, 8192, 512, 1024, nullptr, nullptr);

    // pack fc_W2 into the now-dead ix buffer; out = hid @ fc_W2^T + fc_b2
    unsigned* w2pack = (unsigned*)ix;
    pack_split<<<5000, 256, 0, stream>>>(fc_W2, w2pack, 1280000);
    gemm_mfma<4><<<dim3(79, 64), 256, 0, stream>>>(
        hid, w2pack, fc_b2, nullptr, nullptr, 8192, 10000, 512,
        nullptr, nullptr, nullptr, 0, out);
}